// Round 5
// baseline (306.472 us; speedup 1.0000x reference)
//
#include <hip/hip_runtime.h>
#include <stdint.h>

typedef __bf16 bf16;
typedef bf16 bf16x8 __attribute__((ext_vector_type(8)));
typedef float f32x4 __attribute__((ext_vector_type(4)));

#define MFMA(a, b, c) __builtin_amdgcn_mfma_f32_16x16x32_bf16(a, b, c, 0, 0, 0)

// exp(0.25*s) = exp2(s * 0.25*log2(e)); scale folded into Qp at projection.
#define SCALE_L2E 0.3606737602222409f
#define M0 16.0f

#define WAITVM(N) asm volatile("s_waitcnt vmcnt(" #N ")" ::: "memory")
#define WAITLGKM0 asm volatile("s_waitcnt lgkmcnt(0)" ::: "memory")
#define SBAR __builtin_amdgcn_s_barrier()
#define SCHEDB __builtin_amdgcn_sched_barrier(0)
#define PRIO(x) __builtin_amdgcn_s_setprio(x)

__device__ __forceinline__ void gload_lds16(const void* g, void* l) {
  __builtin_amdgcn_global_load_lds(
      (const __attribute__((address_space(1))) uint32_t*)g,
      (__attribute__((address_space(3))) uint32_t*)l, 16, 0, 0);
}

// ---------------------------------------------------------------------------
// Kernel 1: Wt[z][n][k] = (bf16) W_z[k][n] — LDS-tiled transpose.
// ---------------------------------------------------------------------------
__global__ void k_wtrans(const float* __restrict__ Wq, const float* __restrict__ Wk,
                         const float* __restrict__ Wv, bf16* __restrict__ Wt) {
  __shared__ float tile[32][33];
  int x = threadIdx.x, y = threadIdx.y;
  int k0 = blockIdx.x * 32, n0 = blockIdx.y * 32, z = blockIdx.z;
  const float* W = (z == 0) ? Wq : (z == 1) ? Wk : Wv;
  for (int j = 0; j < 4; j++)
    tile[y + 8 * j][x] = W[(size_t)(k0 + y + 8 * j) * 512 + n0 + x];
  __syncthreads();
  bf16* o = Wt + (size_t)z * 262144;
  for (int j = 0; j < 4; j++)
    o[(size_t)(n0 + y + 8 * j) * 512 + k0 + x] = (bf16)tile[x][y + 8 * j];
}

// ---------------------------------------------------------------------------
// Kernel 2: projection GEMM (unchanged from round 4, counted vmcnt).
// ---------------------------------------------------------------------------
__global__ __launch_bounds__(256, 2) void k_proj(
    const float* __restrict__ q, const float* __restrict__ k, const float* __restrict__ v,
    const bf16* __restrict__ Wt, const float* __restrict__ bq, const float* __restrict__ bk,
    const float* __restrict__ bv, bf16* __restrict__ Qp, bf16* __restrict__ Kp,
    bf16* __restrict__ Vtp) {
  int z = blockIdx.z;
  const float* A = (z == 0) ? q : (z == 1) ? k : v;
  const float* bias = (z == 0) ? bq : (z == 1) ? bk : bv;
  const bf16* Bw = Wt + (size_t)z * 262144;

  int m0 = blockIdx.x * 128, n0 = blockIdx.y * 128;
  __shared__ __align__(16) char smem[65536];
  bf16* As = (bf16*)smem;            // 2 x (128 x 64), swizzled
  bf16* Bs = (bf16*)(smem + 32768);  // 2 x (128 x 64), swizzled
  bf16* Ts = (bf16*)smem;            // epilogue reuse: 128 x 136

  int tid = threadIdx.x;
  int wave = tid >> 6, lane = tid & 63, qr = lane & 15, quad = lane >> 4;
  int wm = (wave >> 1) * 64, wn = (wave & 1) * 64;

  f32x4 acc[4][4];
  for (int mi = 0; mi < 4; mi++)
    for (int ni = 0; ni < 4; ni++) acc[mi][ni] = (f32x4){0.f, 0.f, 0.f, 0.f};

  float4 rx[4], ry[4];

  auto issue = [&](int kk, int buf) {
#pragma unroll
    for (int i = 0; i < 4; i++) {
      int ch = i * 256 + tid, row = ch >> 3, c = ch & 7;
      const float4* src = (const float4*)(A + (size_t)(m0 + row) * 512 + kk + c * 8);
      rx[i] = src[0];
      ry[i] = src[1];
    }
    SCHEDB;  // pin: A f32 loads issued before B gloads
#pragma unroll
    for (int i = 0; i < 4; i++) {
      int ch = i * 256 + tid, row = ch >> 3, c = ch & 7, cs = c ^ (row & 7);
      gload_lds16(Bw + (size_t)(n0 + row) * 512 + kk + cs * 8, &Bs[buf * 8192 + ch * 8]);
    }
    SCHEDB;  // pin: nothing sinks below the B gloads
  };

  auto writeA = [&](int buf) {
#pragma unroll
    for (int i = 0; i < 4; i++) {
      int ch = i * 256 + tid, row = ch >> 3, c = ch & 7, cs = c ^ (row & 7);
      bf16x8 t;
      t[0] = (bf16)rx[i].x; t[1] = (bf16)rx[i].y; t[2] = (bf16)rx[i].z; t[3] = (bf16)rx[i].w;
      t[4] = (bf16)ry[i].x; t[5] = (bf16)ry[i].y; t[6] = (bf16)ry[i].z; t[7] = (bf16)ry[i].w;
      *(bf16x8*)&As[buf * 8192 + row * 64 + cs * 8] = t;
    }
  };

  auto compute = [&](int buf) {
    bf16* Ab = &As[buf * 8192];
    bf16* Bb = &Bs[buf * 8192];
#pragma unroll
    for (int h = 0; h < 2; h++) {
      bf16x8 af[4], bfv[4];
#pragma unroll
      for (int mi = 0; mi < 4; mi++) {
        int rr = wm + mi * 16 + qr;
        int cc = (h * 4 + quad) ^ (rr & 7);
        af[mi] = *(bf16x8*)&Ab[rr * 64 + cc * 8];
      }
#pragma unroll
      for (int ni = 0; ni < 4; ni++) {
        int rr = wn + ni * 16 + qr;
        int cc = (h * 4 + quad) ^ (rr & 7);
        bfv[ni] = *(bf16x8*)&Bb[rr * 64 + cc * 8];
      }
#pragma unroll
      for (int mi = 0; mi < 4; mi++)
#pragma unroll
        for (int ni = 0; ni < 4; ni++) acc[mi][ni] = MFMA(af[mi], bfv[ni], acc[mi][ni]);
    }
  };

  issue(0, 0);
  writeA(0);          // waits A(0); B(0) stays in flight
  WAITLGKM0;
  SBAR;

  for (int t = 0; t < 8; t++) {
    int cur = t & 1;
    if (t < 7) issue((t + 1) * 64, cur ^ 1);  // queue: B(t)x4, A(t+1)x8, B(t+1)x4
    if (t < 7) { WAITVM(12); } else { WAITVM(0); }  // drain B(t) only
    SBAR;   // make ALL waves' B(t) visible before reading Bs
    SCHEDB;
    compute(cur);
    if (t < 7) writeA(cur ^ 1);  // compiler waits A(t+1); B(t+1) still flying
    WAITLGKM0;
    SBAR;
  }

  if (z == 2) {
    for (int ni = 0; ni < 4; ni++) {
      int hcol = wn + ni * 16 + qr;
      float bz = bias[n0 + hcol];
      for (int mi = 0; mi < 4; mi++) {
        int tl = wm + mi * 16 + quad * 4;
        bf16 tmp[4];
        for (int r = 0; r < 4; r++) tmp[r] = (bf16)(acc[mi][ni][r] + bz);
        *(uint64_t*)&Ts[hcol * 136 + tl] = *(uint64_t*)tmp;
      }
    }
    __syncthreads();
    int bb = m0 >> 11, t0l = m0 & 2047;
    for (int i = 0; i < 8; i++) {
      int ch = i * 256 + tid;
      int row = ch >> 4, c = ch & 15;
      *(bf16x8*)(Vtp + (size_t)(bb * 512 + n0 + row) * 2048 + t0l + c * 8) =
          *(bf16x8*)&Ts[row * 136 + c * 8];
    }
  } else {
    bf16* C = (z == 0) ? Qp : Kp;
    float sc = (z == 0) ? SCALE_L2E : 1.0f;
    for (int ni = 0; ni < 4; ni++) {
      int col = n0 + wn + ni * 16 + qr;
      float bz = bias[col];
      for (int mi = 0; mi < 4; mi++) {
        int rbase = m0 + wm + mi * 16 + quad * 4;
        for (int r = 0; r < 4; r++)
          C[(size_t)(rbase + r) * 512 + col] = (bf16)((acc[mi][ni][r] + bz) * sc);
      }
    }
  }
}

// ---------------------------------------------------------------------------
// Kernel 3: FUSED attention. One block per (batch, 64-q-row tile): grid 256,
// block 512 (8 waves), 128 KB dynamic LDS, 1 block/CU.
//   Qs [64 x 512] staged once (swizzled, reused 8 tiles x 8 waves).
//   Loop over 8 KV-tiles of 256 keys:
//     S-phase: S[64 x 256] = Qs . K^T  (K frags direct from L2, no staging;
//              wave w owns kv-cols w*32..w*32+31), d-reduction 8 x 64.
//     P = exp2(S - M0) -> bf16 into Ps[t&1] (dbuf); row-sums -> lacc regs.
//     ONE barrier.  PV-phase: O[64 x 512] += P . V  (V frags direct from L2;
//              wave w owns h-cols w*64..w*64+63), kv-reduction 8 x 32.
//   Epilogue: cross-wave l-reduction in LDS, out = O / l.
// Fixed-M0 softmax (same numerics as the unfused pipeline). blockIdx remap
// b = id & 7 keeps each batch's K/V on one XCD's L2 (4 MB fits).
// ---------------------------------------------------------------------------
__global__ __launch_bounds__(512, 1) void k_attn(const bf16* __restrict__ Qp,
                                                 const bf16* __restrict__ Kp,
                                                 const bf16* __restrict__ Vtp,
                                                 float* __restrict__ out) {
  extern __shared__ __align__(16) char smem[];
  bf16* Qs = (bf16*)smem;            // [64][512] swizzled, 64 KB
  bf16* Ps = (bf16*)(smem + 65536);  // 2 x [64][256] swizzled, 64 KB

  int id = blockIdx.x;
  int b = id & 7, m0 = (id >> 3) * 64;  // all q-tiles of batch b -> same XCD
  const bf16* Qg = Qp + (size_t)b * 2048 * 512;
  const bf16* Kg = Kp + (size_t)b * 2048 * 512;
  const bf16* Vg = Vtp + (size_t)b * 512 * 2048;

  int tid = threadIdx.x;
  int wave = tid >> 6, lane = tid & 63, qr = lane & 15, quad = lane >> 4;

  // stage Q once: 4096 x 16B chunks, 8/thread, pre-swizzled global source
#pragma unroll
  for (int i = 0; i < 8; i++) {
    int ch = i * 512 + tid, row = ch >> 6, c = ch & 63;
    int cs = (c & ~7) | ((c ^ row) & 7);
    gload_lds16(Qg + (size_t)(m0 + row) * 512 + cs * 8, Qs + ch * 8);
  }

  f32x4 acc_o[4][4];
#pragma unroll
  for (int mi = 0; mi < 4; mi++)
#pragma unroll
    for (int ni = 0; ni < 4; ni++) acc_o[mi][ni] = (f32x4){0.f, 0.f, 0.f, 0.f};
  float lacc[4][4];
#pragma unroll
  for (int mi = 0; mi < 4; mi++)
#pragma unroll
    for (int r = 0; r < 4; r++) lacc[mi][r] = 0.f;

  WAITVM(0);
  SBAR;

  for (int t = 0; t < 8; t++) {
    int kv0 = t * 256;
    bf16* Pw = Ps + (t & 1) * 16384;

    // ---------------- S-phase: acc_s[mi][ni], wave kv-slice = wave*32
    f32x4 acc_s[4][2];
#pragma unroll
    for (int mi = 0; mi < 4; mi++)
#pragma unroll
      for (int ni = 0; ni < 2; ni++) acc_s[mi][ni] = (f32x4){0.f, 0.f, 0.f, 0.f};

    for (int d = 0; d < 8; d++) {
      bf16x8 af[4][2], bk_[2][2];
#pragma unroll
      for (int mi = 0; mi < 4; mi++)
#pragma unroll
        for (int kk = 0; kk < 2; kk++) {
          int rr = mi * 16 + qr;
          af[mi][kk] = *(bf16x8*)&Qs[rr * 512 + (d * 8 + ((kk * 4 + quad) ^ (rr & 7))) * 8];
        }
#pragma unroll
      for (int ni = 0; ni < 2; ni++)
#pragma unroll
        for (int kk = 0; kk < 2; kk++) {
          int krow = kv0 + wave * 32 + ni * 16 + qr;
          bk_[ni][kk] = *(const bf16x8*)(Kg + (size_t)krow * 512 + d * 64 + (kk * 4 + quad) * 8);
        }
      PRIO(1);
#pragma unroll
      for (int kk = 0; kk < 2; kk++)
#pragma unroll
        for (int mi = 0; mi < 4; mi++)
#pragma unroll
          for (int ni = 0; ni < 2; ni++)
            acc_s[mi][ni] = MFMA(af[mi][kk], bk_[ni][kk], acc_s[mi][ni]);
      PRIO(0);
    }

    // ---------------- P = exp2(S - M0) -> Ps (swizzled); l partial sums
#pragma unroll
    for (int mi = 0; mi < 4; mi++)
#pragma unroll
      for (int r = 0; r < 4; r++) {
        int row = mi * 16 + quad * 4 + r;
        float srow = 0.f;
#pragma unroll
        for (int ni = 0; ni < 2; ni++) {
          float e = exp2f(acc_s[mi][ni][r] - M0);
          srow += e;
          int col = wave * 32 + ni * 16 + qr;
          int chunk = col >> 3;
          int slot = (chunk & ~7) | ((chunk ^ row) & 7);
          Pw[row * 256 + slot * 8 + (col & 7)] = (bf16)e;
        }
        srow += __shfl_xor(srow, 1);
        srow += __shfl_xor(srow, 2);
        srow += __shfl_xor(srow, 4);
        srow += __shfl_xor(srow, 8);
        lacc[mi][r] += srow;
      }
    WAITLGKM0;
    SBAR;  // P visible to all waves; Ps[t&1^1] (read by PV(t-1)) now dead

    // ---------------- PV-phase: wave h-slice = wave*64
    for (int kk = 0; kk < 8; kk++) {
      bf16x8 ap[4], bv[4];
#pragma unroll
      for (int mi = 0; mi < 4; mi++) {
        int rr = mi * 16 + qr;
        int cidx = kk * 4 + quad;
        int slot = (cidx & ~7) | ((cidx ^ rr) & 7);
        ap[mi] = *(bf16x8*)&Pw[rr * 256 + slot * 8];
      }
#pragma unroll
      for (int ni = 0; ni < 4; ni++) {
        int hrow = wave * 64 + ni * 16 + qr;
        bv[ni] = *(const bf16x8*)(Vg + (size_t)hrow * 2048 + kv0 + (kk * 4 + quad) * 8);
      }
      PRIO(1);
#pragma unroll
      for (int mi = 0; mi < 4; mi++)
#pragma unroll
        for (int ni = 0; ni < 4; ni++)
          acc_o[mi][ni] = MFMA(ap[mi], bv[ni], acc_o[mi][ni]);
      PRIO(0);
    }
    // no barrier: next S writes Ps[other buf]; reuse of THIS buf (t+2) is
    // separated from these reads by the (t+1) barrier.
  }

  // ---------------- cross-wave l-reduction (reuse Qs area)
  WAITLGKM0;
  SBAR;
  float* Lred = (float*)smem;          // [8][64]
  float* Linv = (float*)(smem + 2048); // [64]
  if (qr == 0) {
#pragma unroll
    for (int mi = 0; mi < 4; mi++)
#pragma unroll
      for (int r = 0; r < 4; r++)
        Lred[wave * 64 + mi * 16 + quad * 4 + r] = lacc[mi][r];
  }
  WAITLGKM0;
  SBAR;
  if (tid < 64) {
    float s = 0.f;
#pragma unroll
    for (int w = 0; w < 8; w++) s += Lred[w * 64 + tid];
    Linv[tid] = 1.0f / s;
  }
  WAITLGKM0;
  SBAR;

#pragma unroll
  for (int mi = 0; mi < 4; mi++) {
    int rowl = mi * 16 + quad * 4;
    float linv[4];
#pragma unroll
    for (int r = 0; r < 4; r++) linv[r] = Linv[rowl + r];
#pragma unroll
    for (int ni = 0; ni < 4; ni++) {
      int col = wave * 64 + ni * 16 + qr;
      float* og = out + (size_t)(b * 2048 + m0 + rowl) * 512 + col;
#pragma unroll
      for (int r = 0; r < 4; r++) og[(size_t)r * 512] = acc_o[mi][ni][r] * linv[r];
    }
  }
}

// ---------------------------------------------------------------------------
extern "C" void kernel_launch(void* const* d_in, const int* in_sizes, int n_in,
                              void* d_out, int out_size, void* d_ws, size_t ws_size,
                              hipStream_t stream) {
  (void)in_sizes; (void)n_in; (void)out_size; (void)ws_size;
  const float* q  = (const float*)d_in[0];
  const float* k  = (const float*)d_in[1];
  const float* v  = (const float*)d_in[2];
  const float* Wq = (const float*)d_in[3];
  const float* bq = (const float*)d_in[4];
  const float* Wk = (const float*)d_in[5];
  const float* bk = (const float*)d_in[6];
  const float* Wv = (const float*)d_in[7];
  const float* bv = (const float*)d_in[8];
  float* out = (float*)d_out;

  char* ws = (char*)d_ws;
  bf16* Wt  = (bf16*)(ws);                 // 1,572,864 B
  bf16* Qp  = (bf16*)(ws + 1572864);       // 16 MiB
  bf16* Kp  = (bf16*)(ws + 18350080);      // 16 MiB
  bf16* Vtp = (bf16*)(ws + 35127296);      // 16 MiB (written by k_proj z=2)

  k_wtrans<<<dim3(16, 16, 3), dim3(32, 8, 1), 0, stream>>>(Wq, Wk, Wv, Wt);
  k_proj<<<dim3(128, 4, 3), 256, 0, stream>>>(q, k, v, Wt, bq, bk, bv, Qp, Kp, Vtp);
  k_attn<<<256, 512, 131072, stream>>>(Qp, Kp, Vtp, out);
}

// Round 7
// 272.397 us; speedup vs baseline: 1.1251x; 1.1251x over previous
//
#include <hip/hip_runtime.h>
#include <stdint.h>

typedef __bf16 bf16;
typedef bf16 bf16x8 __attribute__((ext_vector_type(8)));
typedef float f32x4 __attribute__((ext_vector_type(4)));

#define MFMA(a, b, c) __builtin_amdgcn_mfma_f32_16x16x32_bf16(a, b, c, 0, 0, 0)

// exp(0.25*s) = exp2(s * 0.25*log2(e)); scale folded into Qp at projection.
#define SCALE_L2E 0.3606737602222409f
#define M0 16.0f

#define WAITVM(N) asm volatile("s_waitcnt vmcnt(" #N ")" ::: "memory")
#define WAITLGKM0 asm volatile("s_waitcnt lgkmcnt(0)" ::: "memory")
#define SBAR __builtin_amdgcn_s_barrier()
#define SCHEDB __builtin_amdgcn_sched_barrier(0)
#define PRIO(x) __builtin_amdgcn_s_setprio(x)

__device__ __forceinline__ void gload_lds16(const void* g, void* l) {
  __builtin_amdgcn_global_load_lds(
      (const __attribute__((address_space(1))) uint32_t*)g,
      (__attribute__((address_space(3))) uint32_t*)l, 16, 0, 0);
}

// ---------------------------------------------------------------------------
// Kernel 1: Wt[z][n][k] = (bf16) W_z[k][n] — LDS-tiled transpose.
// ---------------------------------------------------------------------------
__global__ void k_wtrans(const float* __restrict__ Wq, const float* __restrict__ Wk,
                         const float* __restrict__ Wv, bf16* __restrict__ Wt) {
  __shared__ float tile[32][33];
  int x = threadIdx.x, y = threadIdx.y;
  int k0 = blockIdx.x * 32, n0 = blockIdx.y * 32, z = blockIdx.z;
  const float* W = (z == 0) ? Wq : (z == 1) ? Wk : Wv;
  for (int j = 0; j < 4; j++)
    tile[y + 8 * j][x] = W[(size_t)(k0 + y + 8 * j) * 512 + n0 + x];
  __syncthreads();
  bf16* o = Wt + (size_t)z * 262144;
  for (int j = 0; j < 4; j++)
    o[(size_t)(n0 + y + 8 * j) * 512 + k0 + x] = (bf16)tile[x][y + 8 * j];
}

// ---------------------------------------------------------------------------
// Kernel 2: projection GEMM, BK=64, 2-DEEP A-register prefetch + counted
// vmcnt. A(t+2) f32 loads issued at tile t (2 tiles of slack ~= HBM latency);
// writeA(t+1) consumes regs loaded a full tile earlier -> no stall.
// Queue at tile t's WAITVM(12): [A(t+1)x8, B(t)x4, A(t+2)x8, B(t+1)x4]
// -> drains B(t) + long-landed A(t+1). Even/odd named reg sets (rule #20),
// loop unrolled x2.
// ---------------------------------------------------------------------------
__global__ __launch_bounds__(256, 2) void k_proj(
    const float* __restrict__ q, const float* __restrict__ k, const float* __restrict__ v,
    const bf16* __restrict__ Wt, const float* __restrict__ bq, const float* __restrict__ bk,
    const float* __restrict__ bv, bf16* __restrict__ Qp, bf16* __restrict__ Kp,
    bf16* __restrict__ Vtp) {
  int z = blockIdx.z;
  const float* A = (z == 0) ? q : (z == 1) ? k : v;
  const float* bias = (z == 0) ? bq : (z == 1) ? bk : bv;
  const bf16* Bw = Wt + (size_t)z * 262144;

  int m0 = blockIdx.x * 128, n0 = blockIdx.y * 128;
  __shared__ __align__(16) char smem[65536];
  bf16* As = (bf16*)smem;            // 2 x (128 x 64), swizzled
  bf16* Bs = (bf16*)(smem + 32768);  // 2 x (128 x 64), swizzled
  bf16* Ts = (bf16*)smem;            // epilogue reuse: 128 x 136

  int tid = threadIdx.x;
  int wave = tid >> 6, lane = tid & 63, qr = lane & 15, quad = lane >> 4;
  int wm = (wave >> 1) * 64, wn = (wave & 1) * 64;

  f32x4 acc[4][4];
  for (int mi = 0; mi < 4; mi++)
    for (int ni = 0; ni < 4; ni++) acc[mi][ni] = (f32x4){0.f, 0.f, 0.f, 0.f};

  float4 rxA[4], ryA[4];  // even A tiles (0,2,4,6)
  float4 rxB[4], ryB[4];  // odd  A tiles (1,3,5,7)

  auto issueA = [&](int kk, float4 (&rx)[4], float4 (&ry)[4]) {
#pragma unroll
    for (int i = 0; i < 4; i++) {
      int ch = i * 256 + tid, row = ch >> 3, c = ch & 7;
      const float4* src = (const float4*)(A + (size_t)(m0 + row) * 512 + kk + c * 8);
      rx[i] = src[0];
      ry[i] = src[1];
    }
    SCHEDB;  // pin issue order (FIFO accounting depends on it)
  };

  auto issueB = [&](int kk, int buf) {
#pragma unroll
    for (int i = 0; i < 4; i++) {
      int ch = i * 256 + tid, row = ch >> 3, c = ch & 7, cs = c ^ (row & 7);
      gload_lds16(Bw + (size_t)(n0 + row) * 512 + kk + cs * 8, &Bs[buf * 8192 + ch * 8]);
    }
    SCHEDB;
  };

  auto writeA = [&](int buf, float4 (&rx)[4], float4 (&ry)[4]) {
#pragma unroll
    for (int i = 0; i < 4; i++) {
      int ch = i * 256 + tid, row = ch >> 3, c = ch & 7, cs = c ^ (row & 7);
      bf16x8 t;
      t[0] = (bf16)rx[i].x; t[1] = (bf16)rx[i].y; t[2] = (bf16)rx[i].z; t[3] = (bf16)rx[i].w;
      t[4] = (bf16)ry[i].x; t[5] = (bf16)ry[i].y; t[6] = (bf16)ry[i].z; t[7] = (bf16)ry[i].w;
      *(bf16x8*)&As[buf * 8192 + row * 64 + cs * 8] = t;
    }
  };

  auto compute = [&](int buf) {
    bf16* Ab = &As[buf * 8192];
    bf16* Bb = &Bs[buf * 8192];
#pragma unroll
    for (int h = 0; h < 2; h++) {
      bf16x8 af[4], bfv[4];
#pragma unroll
      for (int mi = 0; mi < 4; mi++) {
        int rr = wm + mi * 16 + qr;
        int cc = (h * 4 + quad) ^ (rr & 7);
        af[mi] = *(bf16x8*)&Ab[rr * 64 + cc * 8];
      }
#pragma unroll
      for (int ni = 0; ni < 4; ni++) {
        int rr = wn + ni * 16 + qr;
        int cc = (h * 4 + quad) ^ (rr & 7);
        bfv[ni] = *(bf16x8*)&Bb[rr * 64 + cc * 8];
      }
#pragma unroll
      for (int mi = 0; mi < 4; mi++)
#pragma unroll
        for (int ni = 0; ni < 4; ni++) acc[mi][ni] = MFMA(af[mi], bfv[ni], acc[mi][ni]);
    }
  };

  // prologue: queue [A0x8, A1x8, B0x4]; writeA(0) drains A0 -> leaves [A1, B0]
  issueA(0, rxA, ryA);
  issueA(64, rxB, ryB);
  issueB(0, 0);
  writeA(0, rxA, ryA);
  WAITLGKM0;
  SBAR;

#pragma unroll
  for (int t = 0; t < 8; t += 2) {
    // ---- even tile t (buf 0): regs rxA free (A(t) written at t-1)
    if (t < 6) issueA((t + 2) * 64, rxA, ryA);   // A(t+2)
    issueB((t + 1) * 64, 1);                     // B(t+1) -> buf1
    if (t < 6) { WAITVM(12); } else { WAITVM(4); }  // drain B(t) (+ landed A(t+1))
    SBAR;
    SCHEDB;
    compute(0);
    writeA(1, rxB, ryB);                         // A(t+1) -> buf1 (regs landed)
    WAITLGKM0;
    SBAR;

    // ---- odd tile u = t+1 (buf 1)
    int u = t + 1;
    if (u < 6) issueA((u + 2) * 64, rxB, ryB);   // A(u+2)
    if (u < 7) issueB((u + 1) * 64, 0);          // B(u+1) -> buf0
    if (u < 6) { WAITVM(12); } else { WAITVM(0); }  // u==7: drain last B
    SBAR;
    SCHEDB;
    compute(1);
    if (u < 7) writeA(0, rxA, ryA);              // A(u+1) -> buf0
    WAITLGKM0;
    SBAR;
  }

  if (z == 2) {
    for (int ni = 0; ni < 4; ni++) {
      int hcol = wn + ni * 16 + qr;
      float bz = bias[n0 + hcol];
      for (int mi = 0; mi < 4; mi++) {
        int tl = wm + mi * 16 + quad * 4;
        bf16 tmp[4];
        for (int r = 0; r < 4; r++) tmp[r] = (bf16)(acc[mi][ni][r] + bz);
        *(uint64_t*)&Ts[hcol * 136 + tl] = *(uint64_t*)tmp;
      }
    }
    __syncthreads();
    int bb = m0 >> 11, t0l = m0 & 2047;
    for (int i = 0; i < 8; i++) {
      int ch = i * 256 + tid;
      int row = ch >> 4, c = ch & 15;
      *(bf16x8*)(Vtp + (size_t)(bb * 512 + n0 + row) * 2048 + t0l + c * 8) =
          *(bf16x8*)&Ts[row * 136 + c * 8];
    }
  } else {
    bf16* C = (z == 0) ? Qp : Kp;
    float sc = (z == 0) ? SCALE_L2E : 1.0f;
    for (int ni = 0; ni < 4; ni++) {
      int col = n0 + wn + ni * 16 + qr;
      float bz = bias[col];
      for (int mi = 0; mi < 4; mi++) {
        int rbase = m0 + wm + mi * 16 + quad * 4;
        for (int r = 0; r < 4; r++)
          C[(size_t)(rbase + r) * 512 + col] = (bf16)((acc[mi][ni][r] + bz) * sc);
      }
    }
  }
}

// ---------------------------------------------------------------------------
// Kernel 3: QK^T GEMM — 256x256, BK=64, 8 waves (2M x 4N), COUNTED vmcnt.
// (unchanged from round 4 — measured < 69 us)
// ---------------------------------------------------------------------------
__global__ __launch_bounds__(512, 1) void k_qk(const bf16* __restrict__ Qp,
                                               const bf16* __restrict__ Kp,
                                               bf16* __restrict__ P,
                                               float* __restrict__ Lpart) {
  __shared__ __align__(16) bf16 S[65536];  // A: [0,32768) 2 slots; B: [32768,65536)
  int b = blockIdx.z;
  const bf16* A = Qp + (size_t)b * 2048 * 512;
  const bf16* B = Kp + (size_t)b * 2048 * 512;
  bf16* Pb = P + (size_t)b * 2048 * 2048;
  int m0 = blockIdx.x * 256, n0 = blockIdx.y * 256;
  int tid = threadIdx.x;
  int wave = tid >> 6, lane = tid & 63, qr = lane & 15, quad = lane >> 4;
  int wm = wave >> 2, wn = wave & 3;  // 2M x 4N; wave tile 128 x 64

  f32x4 acc[8][4];
  for (int mi = 0; mi < 8; mi++)
    for (int ni = 0; ni < 4; ni++) acc[mi][ni] = (f32x4){0.f, 0.f, 0.f, 0.f};

  auto stageAj = [&](int t, int s, int j) {
    int kk = t * 64;
    bf16* As_ = S + s * 16384;
    int ch = j * 512 + tid, row = ch >> 3, c = ch & 7, cs = c ^ (row & 7);
    gload_lds16(A + (size_t)(m0 + row) * 512 + kk + cs * 8, As_ + ch * 8);
  };
  auto stage = [&](int t, int s) {
    int kk = t * 64;
    bf16* Bs_ = S + 32768 + s * 16384;
#pragma unroll
    for (int j = 0; j < 4; j++) {
      int ch = j * 512 + tid, row = ch >> 3, c = ch & 7, cs = c ^ (row & 7);
      gload_lds16(B + (size_t)(n0 + row) * 512 + kk + cs * 8, Bs_ + ch * 8);
    }
    stageAj(t, s, 0);  // rows   0..63  (phase-1, wm=0)
    stageAj(t, s, 2);  // rows 128..191 (phase-1, wm=1)
    stageAj(t, s, 1);  // rows  64..127 (phase-2, wm=0)
    stageAj(t, s, 3);  // rows 192..255 (phase-2, wm=1)
  };

  stage(0, 0);
  stage(1, 1);  // 16 loads/thread in flight

  for (int t = 0; t < 8; t++) {
    int cur = t & 1;
    bf16* As_ = S + cur * 16384;
    bf16* Bs_ = S + 32768 + cur * 16384;

    // ---- phase 1: drain t's B + A-lo only; read A-lo + all B; 32 MFMA
    if (t < 7) { WAITVM(10); } else { WAITVM(2); }
    SBAR;
    bf16x8 aF[4][2], bF[4][2];
#pragma unroll
    for (int mi = 0; mi < 4; mi++)
#pragma unroll
      for (int kk = 0; kk < 2; kk++) {
        int row = wm * 128 + mi * 16 + qr;
        aF[mi][kk] = *(bf16x8*)&As_[row * 64 + ((kk * 4 + quad) ^ (row & 7)) * 8];
      }
#pragma unroll
    for (int ni = 0; ni < 4; ni++)
#pragma unroll
      for (int kk = 0; kk < 2; kk++) {
        int row = wn * 64 + ni * 16 + qr;
        bF[ni][kk] = *(bf16x8*)&Bs_[row * 64 + ((kk * 4 + quad) ^ (row & 7)) * 8];
      }
    WAITLGKM0;
    SCHEDB;
    PRIO(1);
#pragma unroll
    for (int kk = 0; kk < 2; kk++)
#pragma unroll
      for (int mi = 0; mi < 4; mi++)
#pragma unroll
        for (int ni = 0; ni < 4; ni++)
          acc[mi][ni] = MFMA(aF[mi][kk], bF[ni][kk], acc[mi][ni]);
    PRIO(0);

    // ---- phase 2: drain t's A-hi; read A-hi; restage t+2; 32 MFMA
    if (t < 7) { WAITVM(8); } else { WAITVM(0); }
    SBAR;
#pragma unroll
    for (int mi = 0; mi < 4; mi++)
#pragma unroll
      for (int kk = 0; kk < 2; kk++) {
        int row = wm * 128 + 64 + mi * 16 + qr;
        aF[mi][kk] = *(bf16x8*)&As_[row * 64 + ((kk * 4 + quad) ^ (row & 7)) * 8];
      }
    WAITLGKM0;
    SBAR;  // all waves done reading buf cur -> safe to overwrite
    if (t < 6) stage(t + 2, cur);
    SCHEDB;
    PRIO(1);
#pragma unroll
    for (int kk = 0; kk < 2; kk++)
#pragma unroll
      for (int mi = 0; mi < 4; mi++)
#pragma unroll
        for (int ni = 0; ni < 4; ni++)
          acc[4 + mi][ni] = MFMA(aF[mi][kk], bF[ni][kk], acc[4 + mi][ni]);
    PRIO(0);
  }

  int slice = blockIdx.y * 4 + wn;  // 32 slices of 64 keys
  float* Lp = Lpart + (size_t)slice * 16384 + b * 2048;
#pragma unroll
  for (int mi = 0; mi < 8; mi++) {
    int rowb = m0 + wm * 128 + mi * 16 + quad * 4;
#pragma unroll
    for (int r = 0; r < 4; r++) {
      float s = 0.f;
      bf16* prow = Pb + (size_t)(rowb + r) * 2048 + n0 + wn * 64 + qr;
#pragma unroll
      for (int ni = 0; ni < 4; ni++) {
        float e = exp2f(acc[mi][ni][r] - M0);
        prow[ni * 16] = (bf16)e;
        s += e;
      }
      s += __shfl_xor(s, 1);
      s += __shfl_xor(s, 2);
      s += __shfl_xor(s, 4);
      s += __shfl_xor(s, 8);
      if (qr == 0) Lp[rowb + r] = s;
    }
  }
}

// ---------------------------------------------------------------------------
// Kernel 4: PV GEMM — 256x128, BK=64, 8 waves (4M x 2N), COUNTED vmcnt.
// (unchanged from round 4 — measured < 69 us). grid MUST be (8,4,8):
// m0 = bx*256 over 2048 rows -> 8 x-blocks; 16 was the round-5/6 OOB crash.
// ---------------------------------------------------------------------------
__global__ __launch_bounds__(512, 1) void k_pv(const bf16* __restrict__ P,
                                               const bf16* __restrict__ Vtp,
                                               const float* __restrict__ Lpart,
                                               float* __restrict__ out) {
  __shared__ __align__(16) bf16 S[49152];  // A: [0,32768) 2 slots; B: [32768,49152) 2 slots
  int b = blockIdx.z;
  const bf16* A = P + (size_t)b * 2048 * 2048;
  const bf16* B = Vtp + (size_t)b * 512 * 2048;
  int m0 = blockIdx.x * 256, n0 = blockIdx.y * 128;  // m over q, n over h
  int tid = threadIdx.x;
  int wave = tid >> 6, lane = tid & 63, qr = lane & 15, quad = lane >> 4;
  int wmi = wave >> 1, wni = wave & 1;  // 4M x 2N; wave tile 64 x 64

  float linv_own = 0.f;
  if (tid < 256) {
    float s = 0.f;
    for (int j = 0; j < 32; j++) s += Lpart[(size_t)j * 16384 + b * 2048 + m0 + tid];
    linv_own = 1.0f / s;
  }

  f32x4 acc[4][4];
  for (int mi = 0; mi < 4; mi++)
    for (int ni = 0; ni < 4; ni++) acc[mi][ni] = (f32x4){0.f, 0.f, 0.f, 0.f};

  auto stage = [&](int t, int s) {
    int kk = t * 64;
    bf16* As_ = S + s * 16384;
    bf16* Bs_ = S + 32768 + s * 8192;
#pragma unroll
    for (int j = 0; j < 4; j++) {
      int ch = j * 512 + tid, row = ch >> 3, c = ch & 7, cs = c ^ (row & 7);
      gload_lds16(A + (size_t)(m0 + row) * 2048 + kk + cs * 8, As_ + ch * 8);
    }
#pragma unroll
    for (int j = 0; j < 2; j++) {
      int ch = j * 512 + tid, row = ch >> 3, c = ch & 7, cs = c ^ (row & 7);
      gload_lds16(B + (size_t)(n0 + row) * 2048 + kk + cs * 8, Bs_ + ch * 8);
    }
  };

  stage(0, 0);
  stage(1, 1);  // 12 loads/thread in flight

  for (int t = 0; t < 32; t++) {
    int cur = t & 1;
    bf16* As_ = S + cur * 16384;
    bf16* Bs_ = S + 32768 + cur * 8192;

    if (t < 31) { WAITVM(6); } else { WAITVM(0); }  // drain t, keep t+1 flying
    SBAR;
    bf16x8 aF[4][2], bF[4][2];
#pragma unroll
    for (int mi = 0; mi < 4; mi++)
#pragma unroll
      for (int kk = 0; kk < 2; kk++) {
        int row = wmi * 64 + mi * 16 + qr;
        aF[mi][kk] = *(bf16x8*)&As_[row * 64 + ((kk * 4 + quad) ^ (row & 7)) * 8];
      }
#pragma unroll
    for (int ni = 0; ni < 4; ni++)
#pragma unroll
      for (int kk = 0; kk < 2; kk++) {
        int row = wni * 64 + ni * 16 + qr;
        bF[ni][kk] = *(bf16x8*)&Bs_[row * 64 + ((kk * 4 + quad) ^ (row & 7)) * 8];
      }
    WAITLGKM0;
    SBAR;  // all waves done reading buf cur -> safe to overwrite
    if (t < 30) stage(t + 2, cur);
    SCHEDB;
    PRIO(1);
#pragma unroll
    for (int kk = 0; kk < 2; kk++)
#pragma unroll
      for (int mi = 0; mi < 4; mi++)
#pragma unroll
        for (int ni = 0; ni < 4; ni++)
          acc[mi][ni] = MFMA(aF[mi][kk], bF[ni][kk], acc[mi][ni]);
    PRIO(0);
  }

  // publish Linv via LDS reuse (all reads/stages retired past last barrier)
  WAITLGKM0;
  SBAR;
  float* Linv_s = (float*)S;
  if (tid < 256) Linv_s[tid] = linv_own;
  SBAR;

#pragma unroll
  for (int mi = 0; mi < 4; mi++) {
    int rowl = wmi * 64 + mi * 16 + quad * 4;  // local q row base (0..255)
    float linv[4];
    for (int r = 0; r < 4; r++) linv[r] = Linv_s[rowl + r];
#pragma unroll
    for (int ni = 0; ni < 4; ni++) {
      int col = n0 + wni * 64 + ni * 16 + qr;
      float* og = out + (size_t)(b * 2048 + m0 + rowl) * 512 + col;
      for (int r = 0; r < 4; r++) og[(size_t)r * 512] = acc[mi][ni][r] * linv[r];
    }
  }
}

// ---------------------------------------------------------------------------
extern "C" void kernel_launch(void* const* d_in, const int* in_sizes, int n_in,
                              void* d_out, int out_size, void* d_ws, size_t ws_size,
                              hipStream_t stream) {
  (void)in_sizes; (void)n_in; (void)out_size; (void)ws_size;
  const float* q  = (const float*)d_in[0];
  const float* k  = (const float*)d_in[1];
  const float* v  = (const float*)d_in[2];
  const float* Wq = (const float*)d_in[3];
  const float* bq = (const float*)d_in[4];
  const float* Wk = (const float*)d_in[5];
  const float* bk = (const float*)d_in[6];
  const float* Wv = (const float*)d_in[7];
  const float* bv = (const float*)d_in[8];
  float* out = (float*)d_out;

  char* ws = (char*)d_ws;
  bf16* Wt     = (bf16*)(ws);                 // 1,572,864 B
  bf16* Qp     = (bf16*)(ws + 1572864);       // 16 MiB
  bf16* Kp     = (bf16*)(ws + 18350080);      // 16 MiB
  bf16* Vtp    = (bf16*)(ws + 35127296);      // 16 MiB (written by k_proj z=2)
  bf16* P      = (bf16*)(ws + 51904512);      // 64 MiB
  float* Lpart = (float*)(ws + 119013376);    // 2 MiB  (total ~115.4 MiB)

  k_wtrans<<<dim3(16, 16, 3), dim3(32, 8, 1), 0, stream>>>(Wq, Wk, Wv, Wt);
  k_proj<<<dim3(128, 4, 3), 256, 0, stream>>>(q, k, v, Wt, bq, bk, bv, Qp, Kp, Vtp);
  k_qk<<<dim3(8, 8, 8), 512, 0, stream>>>(Qp, Kp, P, Lpart);
  k_pv<<<dim3(8, 4, 8), 512, 0, stream>>>(P, Vtp, Lpart, out);
}

// Round 9
// 261.559 us; speedup vs baseline: 1.1717x; 1.0414x over previous
//
#include <hip/hip_runtime.h>
#include <stdint.h>

typedef __bf16 bf16;
typedef bf16 bf16x8 __attribute__((ext_vector_type(8)));
typedef float f32x4 __attribute__((ext_vector_type(4)));

#define MFMA(a, b, c) __builtin_amdgcn_mfma_f32_16x16x32_bf16(a, b, c, 0, 0, 0)

// exp(0.25*s) = exp2(s * 0.25*log2(e)); scale folded into Qp at projection.
#define SCALE_L2E 0.3606737602222409f
#define M0 16.0f

#define WAITVM(N) asm volatile("s_waitcnt vmcnt(" #N ")" ::: "memory")
#define WAITLGKM0 asm volatile("s_waitcnt lgkmcnt(0)" ::: "memory")
#define SBAR __builtin_amdgcn_s_barrier()
#define SCHEDB __builtin_amdgcn_sched_barrier(0)
#define PRIO(x) __builtin_amdgcn_s_setprio(x)

__device__ __forceinline__ void gload_lds16(const void* g, void* l) {
  __builtin_amdgcn_global_load_lds(
      (const __attribute__((address_space(1))) uint32_t*)g,
      (__attribute__((address_space(3))) uint32_t*)l, 16, 0, 0);
}

// ---------------------------------------------------------------------------
// Kernel 1: Wt[z][n][k] = (bf16) W_z[k][n] — LDS-tiled transpose.
// ---------------------------------------------------------------------------
__global__ void k_wtrans(const float* __restrict__ Wq, const float* __restrict__ Wk,
                         const float* __restrict__ Wv, bf16* __restrict__ Wt) {
  __shared__ float tile[32][33];
  int x = threadIdx.x, y = threadIdx.y;
  int k0 = blockIdx.x * 32, n0 = blockIdx.y * 32, z = blockIdx.z;
  const float* W = (z == 0) ? Wq : (z == 1) ? Wk : Wv;
  for (int j = 0; j < 4; j++)
    tile[y + 8 * j][x] = W[(size_t)(k0 + y + 8 * j) * 512 + n0 + x];
  __syncthreads();
  bf16* o = Wt + (size_t)z * 262144;
  for (int j = 0; j < 4; j++)
    o[(size_t)(n0 + y + 8 * j) * 512 + k0 + x] = (bf16)tile[x][y + 8 * j];
}

// ---------------------------------------------------------------------------
// Kernel 2: projection GEMM, BK=64, 3 blocks/CU (48 KB LDS):
//  - As: SINGLE 16 KB buffer, T14 reg-staged (A f32 loads issued 1 tile early,
//    cvt+ds_write after the read-complete barrier).
//  - Bs: 2 x 16 KB gload_lds double-buffer, counted vmcnt.
// Queue at tile t's WAITVM(20): [B(t)x4, A(t+1)x8, B(t+1)x4, A(t+2)x8]
// -> drains B(t) only; writeA's compiler-counted wait drains A(t).
// NOTE: issueA/issueB take ELEMENT offsets (tile*64) — r8's bug was passing
// tile indices here.
// ---------------------------------------------------------------------------
__global__ __launch_bounds__(256, 3) void k_proj(
    const float* __restrict__ q, const float* __restrict__ k, const float* __restrict__ v,
    const bf16* __restrict__ Wt, const float* __restrict__ bq, const float* __restrict__ bk,
    const float* __restrict__ bv, bf16* __restrict__ Qp, bf16* __restrict__ Kp,
    bf16* __restrict__ Vtp) {
  int z = blockIdx.z;
  const float* A = (z == 0) ? q : (z == 1) ? k : v;
  const float* bias = (z == 0) ? bq : (z == 1) ? bk : bv;
  const bf16* Bw = Wt + (size_t)z * 262144;

  int m0 = blockIdx.x * 128, n0 = blockIdx.y * 128;
  __shared__ __align__(16) char smem[49152];
  bf16* As = (bf16*)smem;            // 128 x 64 single, swizzled (16 KB)
  bf16* Bs = (bf16*)(smem + 16384);  // 2 x (128 x 64), gload dbuf (32 KB)
  bf16* Ts = (bf16*)smem;            // epilogue reuse: 128 x 136 (34816 B)

  int tid = threadIdx.x;
  int wave = tid >> 6, lane = tid & 63, qr = lane & 15, quad = lane >> 4;
  int wm = (wave >> 1) * 64, wn = (wave & 1) * 64;

  f32x4 acc[4][4];
  for (int mi = 0; mi < 4; mi++)
    for (int ni = 0; ni < 4; ni++) acc[mi][ni] = (f32x4){0.f, 0.f, 0.f, 0.f};

  float4 rxE[4], ryE[4];  // A regs, even tiles
  float4 rxO[4], ryO[4];  // A regs, odd tiles

  auto issueA = [&](int kk, float4 (&rx)[4], float4 (&ry)[4]) {
#pragma unroll
    for (int i = 0; i < 4; i++) {
      int ch = i * 256 + tid, row = ch >> 3, c = ch & 7;
      const float4* src = (const float4*)(A + (size_t)(m0 + row) * 512 + kk + c * 8);
      rx[i] = src[0];
      ry[i] = src[1];
    }
    SCHEDB;  // pin issue order (vmcnt FIFO accounting depends on it)
  };

  auto issueB = [&](int kk, int buf) {
#pragma unroll
    for (int i = 0; i < 4; i++) {
      int ch = i * 256 + tid, row = ch >> 3, c = ch & 7, cs = c ^ (row & 7);
      gload_lds16(Bw + (size_t)(n0 + row) * 512 + kk + cs * 8, &Bs[buf * 8192 + ch * 8]);
    }
    SCHEDB;
  };

  auto writeA = [&](float4 (&rx)[4], float4 (&ry)[4]) {
#pragma unroll
    for (int i = 0; i < 4; i++) {
      int ch = i * 256 + tid, row = ch >> 3, c = ch & 7, cs = c ^ (row & 7);
      bf16x8 t;
      t[0] = (bf16)rx[i].x; t[1] = (bf16)rx[i].y; t[2] = (bf16)rx[i].z; t[3] = (bf16)rx[i].w;
      t[4] = (bf16)ry[i].x; t[5] = (bf16)ry[i].y; t[6] = (bf16)ry[i].z; t[7] = (bf16)ry[i].w;
      *(bf16x8*)&As[row * 64 + cs * 8] = t;
    }
  };

  auto compute = [&](int buf) {
    bf16* Bb = &Bs[buf * 8192];
#pragma unroll
    for (int h = 0; h < 2; h++) {
      bf16x8 af[4], bfv[4];
#pragma unroll
      for (int mi = 0; mi < 4; mi++) {
        int rr = wm + mi * 16 + qr;
        int cc = (h * 4 + quad) ^ (rr & 7);
        af[mi] = *(bf16x8*)&As[rr * 64 + cc * 8];
      }
#pragma unroll
      for (int ni = 0; ni < 4; ni++) {
        int rr = wn + ni * 16 + qr;
        int cc = (h * 4 + quad) ^ (rr & 7);
        bfv[ni] = *(bf16x8*)&Bb[rr * 64 + cc * 8];
      }
#pragma unroll
      for (int mi = 0; mi < 4; mi++)
#pragma unroll
        for (int ni = 0; ni < 4; ni++) acc[mi][ni] = MFMA(af[mi], bfv[ni], acc[mi][ni]);
    }
  };

  // prologue queue: [A0x8, B0x4, A1x8]
  issueA(0, rxE, ryE);
  issueB(0, 0);
  issueA(64, rxO, ryO);

#pragma unroll
  for (int t = 0; t < 8; t += 2) {
    // ---- even tile t (Bs buf0, A set E)
    writeA(rxE, ryE);                              // compiler waits A(t)
    issueB((t + 1) * 64, 1);                       // B(t+1) -> buf1
    if (t < 6) issueA((t + 2) * 64, rxE, ryE);     // A(t+2) into freed set E
    if (t < 6) { WAITVM(20); } else { WAITVM(12); }  // drain B(t) only
    WAITLGKM0;
    SBAR;
    SCHEDB;
    compute(0);
    SBAR;                                          // all waves done reading

    // ---- odd tile u = t+1 (Bs buf1, A set O)
    int u = t + 1;
    writeA(rxO, ryO);                              // compiler waits A(u)
    if (u < 7) issueB((u + 1) * 64, 0);            // B(u+1) -> buf0
    if (u < 6) issueA((u + 2) * 64, rxO, ryO);     // A(u+2) into freed set O
    if (u < 6) { WAITVM(20); } else if (u < 7) { WAITVM(12); } else { WAITVM(0); }
    WAITLGKM0;
    SBAR;
    SCHEDB;
    compute(1);
    SBAR;
  }

  if (z == 2) {
    for (int ni = 0; ni < 4; ni++) {
      int hcol = wn + ni * 16 + qr;
      float bz = bias[n0 + hcol];
      for (int mi = 0; mi < 4; mi++) {
        int tl = wm + mi * 16 + quad * 4;
        bf16 tmp[4];
        for (int r = 0; r < 4; r++) tmp[r] = (bf16)(acc[mi][ni][r] + bz);
        *(uint64_t*)&Ts[hcol * 136 + tl] = *(uint64_t*)tmp;
      }
    }
    __syncthreads();
    int bb = m0 >> 11, t0l = m0 & 2047;
    for (int i = 0; i < 8; i++) {
      int ch = i * 256 + tid;
      int row = ch >> 4, c = ch & 15;
      *(bf16x8*)(Vtp + (size_t)(bb * 512 + n0 + row) * 2048 + t0l + c * 8) =
          *(bf16x8*)&Ts[row * 136 + c * 8];
    }
  } else {
    bf16* C = (z == 0) ? Qp : Kp;
    float sc = (z == 0) ? SCALE_L2E : 1.0f;
    for (int ni = 0; ni < 4; ni++) {
      int col = n0 + wn + ni * 16 + qr;
      float bz = bias[col];
      for (int mi = 0; mi < 4; mi++) {
        int rbase = m0 + wm + mi * 16 + quad * 4;
        for (int r = 0; r < 4; r++)
          C[(size_t)(rbase + r) * 512 + col] = (bf16)((acc[mi][ni][r] + bz) * sc);
      }
    }
  }
}

// ---------------------------------------------------------------------------
// Kernel 3: QK^T GEMM — 256x256, BK=64, 8 waves, COUNTED vmcnt (r4 body).
// XCD batch-pinning: 1D grid, id = j*8 + b -> id%8 = b -> all blocks of
// batch b on XCD b; L2 (4 MB) holds Qp_b+Kp_b (4 MB).
// ---------------------------------------------------------------------------
__global__ __launch_bounds__(512, 1) void k_qk(const bf16* __restrict__ Qp,
                                               const bf16* __restrict__ Kp,
                                               bf16* __restrict__ P,
                                               float* __restrict__ Lpart) {
  __shared__ __align__(16) bf16 S[65536];  // A: [0,32768) 2 slots; B: [32768,65536)
  int id = blockIdx.x;
  int b = id & 7, j = id >> 3;
  int mx = j & 7, ny = j >> 3;
  const bf16* A = Qp + (size_t)b * 2048 * 512;
  const bf16* B = Kp + (size_t)b * 2048 * 512;
  bf16* Pb = P + (size_t)b * 2048 * 2048;
  int m0 = mx * 256, n0 = ny * 256;
  int tid = threadIdx.x;
  int wave = tid >> 6, lane = tid & 63, qr = lane & 15, quad = lane >> 4;
  int wm = wave >> 2, wn = wave & 3;  // 2M x 4N; wave tile 128 x 64

  f32x4 acc[8][4];
  for (int mi = 0; mi < 8; mi++)
    for (int ni = 0; ni < 4; ni++) acc[mi][ni] = (f32x4){0.f, 0.f, 0.f, 0.f};

  auto stageAj = [&](int t, int s, int jj) {
    int kk = t * 64;
    bf16* As_ = S + s * 16384;
    int ch = jj * 512 + tid, row = ch >> 3, c = ch & 7, cs = c ^ (row & 7);
    gload_lds16(A + (size_t)(m0 + row) * 512 + kk + cs * 8, As_ + ch * 8);
  };
  auto stage = [&](int t, int s) {
    int kk = t * 64;
    bf16* Bs_ = S + 32768 + s * 16384;
#pragma unroll
    for (int jj = 0; jj < 4; jj++) {
      int ch = jj * 512 + tid, row = ch >> 3, c = ch & 7, cs = c ^ (row & 7);
      gload_lds16(B + (size_t)(n0 + row) * 512 + kk + cs * 8, Bs_ + ch * 8);
    }
    stageAj(t, s, 0);  // rows   0..63  (phase-1, wm=0)
    stageAj(t, s, 2);  // rows 128..191 (phase-1, wm=1)
    stageAj(t, s, 1);  // rows  64..127 (phase-2, wm=0)
    stageAj(t, s, 3);  // rows 192..255 (phase-2, wm=1)
  };

  stage(0, 0);
  stage(1, 1);  // 16 loads/thread in flight

  for (int t = 0; t < 8; t++) {
    int cur = t & 1;
    bf16* As_ = S + cur * 16384;
    bf16* Bs_ = S + 32768 + cur * 16384;

    // ---- phase 1: drain t's B + A-lo only; read A-lo + all B; 32 MFMA
    if (t < 7) { WAITVM(10); } else { WAITVM(2); }
    SBAR;
    bf16x8 aF[4][2], bF[4][2];
#pragma unroll
    for (int mi = 0; mi < 4; mi++)
#pragma unroll
      for (int kk = 0; kk < 2; kk++) {
        int row = wm * 128 + mi * 16 + qr;
        aF[mi][kk] = *(bf16x8*)&As_[row * 64 + ((kk * 4 + quad) ^ (row & 7)) * 8];
      }
#pragma unroll
    for (int ni = 0; ni < 4; ni++)
#pragma unroll
      for (int kk = 0; kk < 2; kk++) {
        int row = wn * 64 + ni * 16 + qr;
        bF[ni][kk] = *(bf16x8*)&Bs_[row * 64 + ((kk * 4 + quad) ^ (row & 7)) * 8];
      }
    WAITLGKM0;
    SCHEDB;
    PRIO(1);
#pragma unroll
    for (int kk = 0; kk < 2; kk++)
#pragma unroll
      for (int mi = 0; mi < 4; mi++)
#pragma unroll
        for (int ni = 0; ni < 4; ni++)
          acc[mi][ni] = MFMA(aF[mi][kk], bF[ni][kk], acc[mi][ni]);
    PRIO(0);

    // ---- phase 2: drain t's A-hi; read A-hi; restage t+2; 32 MFMA
    if (t < 7) { WAITVM(8); } else { WAITVM(0); }
    SBAR;
#pragma unroll
    for (int mi = 0; mi < 4; mi++)
#pragma unroll
      for (int kk = 0; kk < 2; kk++) {
        int row = wm * 128 + 64 + mi * 16 + qr;
        aF[mi][kk] = *(bf16x8*)&As_[row * 64 + ((kk * 4 + quad) ^ (row & 7)) * 8];
      }
    WAITLGKM0;
    SBAR;  // all waves done reading buf cur -> safe to overwrite
    if (t < 6) stage(t + 2, cur);
    SCHEDB;
    PRIO(1);
#pragma unroll
    for (int kk = 0; kk < 2; kk++)
#pragma unroll
      for (int mi = 0; mi < 4; mi++)
#pragma unroll
        for (int ni = 0; ni < 4; ni++)
          acc[4 + mi][ni] = MFMA(aF[mi][kk], bF[ni][kk], acc[4 + mi][ni]);
    PRIO(0);
  }

  int slice = ny * 4 + wn;  // 32 slices of 64 keys
  float* Lp = Lpart + (size_t)slice * 16384 + b * 2048;
#pragma unroll
  for (int mi = 0; mi < 8; mi++) {
    int rowb = m0 + wm * 128 + mi * 16 + quad * 4;
#pragma unroll
    for (int r = 0; r < 4; r++) {
      float s = 0.f;
      bf16* prow = Pb + (size_t)(rowb + r) * 2048 + n0 + wn * 64 + qr;
#pragma unroll
      for (int ni = 0; ni < 4; ni++) {
        float e = exp2f(acc[mi][ni][r] - M0);
        prow[ni * 16] = (bf16)e;
        s += e;
      }
      s += __shfl_xor(s, 1);
      s += __shfl_xor(s, 2);
      s += __shfl_xor(s, 4);
      s += __shfl_xor(s, 8);
      if (qr == 0) Lp[rowb + r] = s;
    }
  }
}

// ---------------------------------------------------------------------------
// Kernel 4: PV GEMM — 256x128, BK=64, 8 waves, COUNTED vmcnt (r4 body).
// XCD batch-pinning: 1D grid, id = j*8 + b (32 blocks/batch -> one XCD).
// ---------------------------------------------------------------------------
__global__ __launch_bounds__(512, 1) void k_pv(const bf16* __restrict__ P,
                                               const bf16* __restrict__ Vtp,
                                               const float* __restrict__ Lpart,
                                               float* __restrict__ out) {
  __shared__ __align__(16) bf16 S[49152];  // A: [0,32768) 2 slots; B: [32768,49152) 2 slots
  int id = blockIdx.x;
  int b = id & 7, j = id >> 3;
  int mx = j & 7, ny = j >> 3;
  const bf16* A = P + (size_t)b * 2048 * 2048;
  const bf16* B = Vtp + (size_t)b * 512 * 2048;
  int m0 = mx * 256, n0 = ny * 128;  // m over q, n over h
  int tid = threadIdx.x;
  int wave = tid >> 6, lane = tid & 63, qr = lane & 15, quad = lane >> 4;
  int wmi = wave >> 1, wni = wave & 1;  // 4M x 2N; wave tile 64 x 64

  float linv_own = 0.f;
  if (tid < 256) {
    float s = 0.f;
    for (int jj = 0; jj < 32; jj++) s += Lpart[(size_t)jj * 16384 + b * 2048 + m0 + tid];
    linv_own = 1.0f / s;
  }

  f32x4 acc[4][4];
  for (int mi = 0; mi < 4; mi++)
    for (int ni = 0; ni < 4; ni++) acc[mi][ni] = (f32x4){0.f, 0.f, 0.f, 0.f};

  auto stage = [&](int t, int s) {
    int kk = t * 64;
    bf16* As_ = S + s * 16384;
    bf16* Bs_ = S + 32768 + s * 8192;
#pragma unroll
    for (int jj = 0; jj < 4; jj++) {
      int ch = jj * 512 + tid, row = ch >> 3, c = ch & 7, cs = c ^ (row & 7);
      gload_lds16(A + (size_t)(m0 + row) * 2048 + kk + cs * 8, As_ + ch * 8);
    }
#pragma unroll
    for (int jj = 0; jj < 2; jj++) {
      int ch = jj * 512 + tid, row = ch >> 3, c = ch & 7, cs = c ^ (row & 7);
      gload_lds16(B + (size_t)(n0 + row) * 2048 + kk + cs * 8, Bs_ + ch * 8);
    }
  };

  stage(0, 0);
  stage(1, 1);  // 12 loads/thread in flight

  for (int t = 0; t < 32; t++) {
    int cur = t & 1;
    bf16* As_ = S + cur * 16384;
    bf16* Bs_ = S + 32768 + cur * 8192;

    if (t < 31) { WAITVM(6); } else { WAITVM(0); }  // drain t, keep t+1 flying
    SBAR;
    bf16x8 aF[4][2], bF[4][2];
#pragma unroll
    for (int mi = 0; mi < 4; mi++)
#pragma unroll
      for (int kk = 0; kk < 2; kk++) {
        int row = wmi * 64 + mi * 16 + qr;
        aF[mi][kk] = *(bf16x8*)&As_[row * 64 + ((kk * 4 + quad) ^ (row & 7)) * 8];
      }
#pragma unroll
    for (int ni = 0; ni < 4; ni++)
#pragma unroll
      for (int kk = 0; kk < 2; kk++) {
        int row = wni * 64 + ni * 16 + qr;
        bF[ni][kk] = *(bf16x8*)&Bs_[row * 64 + ((kk * 4 + quad) ^ (row & 7)) * 8];
      }
    WAITLGKM0;
    SBAR;  // all waves done reading buf cur -> safe to overwrite
    if (t < 30) stage(t + 2, cur);
    SCHEDB;
    PRIO(1);
#pragma unroll
    for (int kk = 0; kk < 2; kk++)
#pragma unroll
      for (int mi = 0; mi < 4; mi++)
#pragma unroll
        for (int ni = 0; ni < 4; ni++)
          acc[mi][ni] = MFMA(aF[mi][kk], bF[ni][kk], acc[mi][ni]);
    PRIO(0);
  }

  // publish Linv via LDS reuse (all reads/stages retired past last barrier)
  WAITLGKM0;
  SBAR;
  float* Linv_s = (float*)S;
  if (tid < 256) Linv_s[tid] = linv_own;
  SBAR;

#pragma unroll
  for (int mi = 0; mi < 4; mi++) {
    int rowl = wmi * 64 + mi * 16 + quad * 4;  // local q row base (0..255)
    float linv[4];
    for (int r = 0; r < 4; r++) linv[r] = Linv_s[rowl + r];
#pragma unroll
    for (int ni = 0; ni < 4; ni++) {
      int col = n0 + wni * 64 + ni * 16 + qr;
      float* og = out + (size_t)(b * 2048 + m0 + rowl) * 512 + col;
      for (int r = 0; r < 4; r++) og[(size_t)r * 512] = acc[mi][ni][r] * linv[r];
    }
  }
}

// ---------------------------------------------------------------------------
extern "C" void kernel_launch(void* const* d_in, const int* in_sizes, int n_in,
                              void* d_out, int out_size, void* d_ws, size_t ws_size,
                              hipStream_t stream) {
  (void)in_sizes; (void)n_in; (void)out_size; (void)ws_size;
  const float* q  = (const float*)d_in[0];
  const float* k  = (const float*)d_in[1];
  const float* v  = (const float*)d_in[2];
  const float* Wq = (const float*)d_in[3];
  const float* bq = (const float*)d_in[4];
  const float* Wk = (const float*)d_in[5];
  const float* bk = (const float*)d_in[6];
  const float* Wv = (const float*)d_in[7];
  const float* bv = (const float*)d_in[8];
  float* out = (float*)d_out;

  char* ws = (char*)d_ws;
  bf16* Wt     = (bf16*)(ws);                 // 1,572,864 B
  bf16* Qp     = (bf16*)(ws + 1572864);       // 16 MiB
  bf16* Kp     = (bf16*)(ws + 18350080);      // 16 MiB
  bf16* Vtp    = (bf16*)(ws + 35127296);      // 16 MiB (written by k_proj z=2)
  bf16* P      = (bf16*)(ws + 51904512);      // 64 MiB
  float* Lpart = (float*)(ws + 119013376);    // 2 MiB  (total ~115.4 MiB)

  k_wtrans<<<dim3(16, 16, 3), dim3(32, 8, 1), 0, stream>>>(Wq, Wk, Wv, Wt);
  k_proj<<<dim3(128, 4, 3), 256, 0, stream>>>(q, k, v, Wt, bq, bk, bv, Qp, Kp, Vtp);
  k_qk<<<512, 512, 0, stream>>>(Qp, Kp, P, Lpart);
  k_pv<<<256, 512, 0, stream>>>(P, Vtp, Lpart, out);
}

// Round 10
// 259.313 us; speedup vs baseline: 1.1819x; 1.0087x over previous
//
#include <hip/hip_runtime.h>
#include <stdint.h>

typedef __bf16 bf16;
typedef bf16 bf16x8 __attribute__((ext_vector_type(8)));
typedef float f32x4 __attribute__((ext_vector_type(4)));

#define MFMA(a, b, c) __builtin_amdgcn_mfma_f32_16x16x32_bf16(a, b, c, 0, 0, 0)

// exp(0.25*s) = exp2(s * 0.25*log2(e)); scale folded into Qp at projection.
#define SCALE_L2E 0.3606737602222409f
#define M0 16.0f

#define WAITVM(N) asm volatile("s_waitcnt vmcnt(" #N ")" ::: "memory")
#define WAITLGKM0 asm volatile("s_waitcnt lgkmcnt(0)" ::: "memory")
#define SBAR __builtin_amdgcn_s_barrier()
#define SCHEDB __builtin_amdgcn_sched_barrier(0)
#define PRIO(x) __builtin_amdgcn_s_setprio(x)

__device__ __forceinline__ void gload_lds16(const void* g, void* l) {
  __builtin_amdgcn_global_load_lds(
      (const __attribute__((address_space(1))) uint32_t*)g,
      (__attribute__((address_space(3))) uint32_t*)l, 16, 0, 0);
}

// ---------------------------------------------------------------------------
// Kernel 1: Wt[z][n][k] = (bf16) W_z[k][n] — LDS-tiled transpose.
// ---------------------------------------------------------------------------
__global__ void k_wtrans(const float* __restrict__ Wq, const float* __restrict__ Wk,
                         const float* __restrict__ Wv, bf16* __restrict__ Wt) {
  __shared__ float tile[32][33];
  int x = threadIdx.x, y = threadIdx.y;
  int k0 = blockIdx.x * 32, n0 = blockIdx.y * 32, z = blockIdx.z;
  const float* W = (z == 0) ? Wq : (z == 1) ? Wk : Wv;
  for (int j = 0; j < 4; j++)
    tile[y + 8 * j][x] = W[(size_t)(k0 + y + 8 * j) * 512 + n0 + x];
  __syncthreads();
  bf16* o = Wt + (size_t)z * 262144;
  for (int j = 0; j < 4; j++)
    o[(size_t)(n0 + y + 8 * j) * 512 + k0 + x] = (bf16)tile[x][y + 8 * j];
}

// ---------------------------------------------------------------------------
// Kernel 2a: Q/K projection — FULL-N blocks: 128 rows x 512 cols, 8 waves
// (2M x 4N, wave tile 64x128). A (f32) staged ONCE per row-block (was 4x):
// single As buffer, reg-staged (T14, even/odd reg sets). Bs = [512][64]
// gload_lds double-buffer. Counted vmcnt: queue at tile t =
// [B(t)x8, A(t+1)x4, B(t+1)x8, A(t+2)x4] -> WAITVM(16) drains B(t) only.
// grid (128, 2): y=0 -> Qp (SCALE folded), y=1 -> Kp. 144 KB dynamic LDS.
// ---------------------------------------------------------------------------
__global__ __launch_bounds__(512, 1) void k_proj2(
    const float* __restrict__ q, const float* __restrict__ k,
    const bf16* __restrict__ Wt, const float* __restrict__ bq,
    const float* __restrict__ bk, bf16* __restrict__ Qp, bf16* __restrict__ Kp) {
  int z = blockIdx.y;
  const float* A = (z == 0) ? q : k;
  const float* bias = (z == 0) ? bq : bk;
  const bf16* Bw = Wt + (size_t)z * 262144;
  bf16* C = (z == 0) ? Qp : Kp;
  float sc = (z == 0) ? SCALE_L2E : 1.0f;

  int m0 = blockIdx.x * 128;
  extern __shared__ __align__(16) char smem[];
  bf16* As = (bf16*)smem;            // [128][64] single, swizzled (16 KB)
  bf16* Bs = (bf16*)(smem + 16384);  // 2 x [512][64], gload dbuf (128 KB)

  int tid = threadIdx.x;
  int wave = tid >> 6, lane = tid & 63, qr = lane & 15, quad = lane >> 4;
  int wm2 = wave >> 2, wn4 = wave & 3;  // 2M x 4N; wave tile 64 x 128

  f32x4 acc[4][8];
  for (int mi = 0; mi < 4; mi++)
    for (int ni = 0; ni < 8; ni++) acc[mi][ni] = (f32x4){0.f, 0.f, 0.f, 0.f};

  float4 rxE[2], ryE[2];  // A regs, even tiles
  float4 rxO[2], ryO[2];  // A regs, odd tiles

  auto issueA = [&](int kk, float4 (&rx)[2], float4 (&ry)[2]) {
#pragma unroll
    for (int i = 0; i < 2; i++) {
      int ch = i * 512 + tid, row = ch >> 3, c = ch & 7;
      const float4* src = (const float4*)(A + (size_t)(m0 + row) * 512 + kk + c * 8);
      rx[i] = src[0];
      ry[i] = src[1];
    }
    SCHEDB;  // pin issue order (vmcnt FIFO accounting)
  };

  auto issueB = [&](int kk, int buf) {
#pragma unroll
    for (int j = 0; j < 8; j++) {
      int ch = j * 512 + tid, row = ch >> 3, c = ch & 7, cs = c ^ (row & 7);
      gload_lds16(Bw + (size_t)row * 512 + kk + cs * 8, &Bs[buf * 32768 + ch * 8]);
    }
    SCHEDB;
  };

  auto writeA = [&](float4 (&rx)[2], float4 (&ry)[2]) {
#pragma unroll
    for (int i = 0; i < 2; i++) {
      int ch = i * 512 + tid, row = ch >> 3, c = ch & 7, cs = c ^ (row & 7);
      bf16x8 t;
      t[0] = (bf16)rx[i].x; t[1] = (bf16)rx[i].y; t[2] = (bf16)rx[i].z; t[3] = (bf16)rx[i].w;
      t[4] = (bf16)ry[i].x; t[5] = (bf16)ry[i].y; t[6] = (bf16)ry[i].z; t[7] = (bf16)ry[i].w;
      *(bf16x8*)&As[row * 64 + cs * 8] = t;
    }
  };

  auto compute = [&](int buf) {
    bf16* Bb = &Bs[buf * 32768];
#pragma unroll
    for (int kk = 0; kk < 2; kk++) {
      bf16x8 af[4];
#pragma unroll
      for (int mi = 0; mi < 4; mi++) {
        int rr = wm2 * 64 + mi * 16 + qr;
        af[mi] = *(bf16x8*)&As[rr * 64 + (((kk * 4 + quad)) ^ (rr & 7)) * 8];
      }
#pragma unroll
      for (int ni = 0; ni < 8; ni++) {
        int rr = wn4 * 128 + ni * 16 + qr;
        bf16x8 bfv = *(bf16x8*)&Bb[rr * 64 + (((kk * 4 + quad)) ^ (rr & 7)) * 8];
#pragma unroll
        for (int mi = 0; mi < 4; mi++) acc[mi][ni] = MFMA(af[mi], bfv, acc[mi][ni]);
      }
    }
  };

  // prologue queue: [A0x4, B0x8, A1x4]
  issueA(0, rxE, ryE);
  issueB(0, 0);
  issueA(64, rxO, ryO);

#pragma unroll
  for (int t = 0; t < 8; t += 2) {
    // ---- even tile t (Bs buf0, A set E)
    writeA(rxE, ryE);                              // compiler waits A(t)
    issueB((t + 1) * 64, 1);                       // B(t+1) -> buf1
    if (t < 6) issueA((t + 2) * 64, rxE, ryE);     // A(t+2)
    if (t < 6) { WAITVM(16); } else { WAITVM(12); }  // drain B(t) only
    WAITLGKM0;
    SBAR;
    SCHEDB;
    compute(0);
    SBAR;                                          // all waves done reading

    // ---- odd tile u = t+1 (Bs buf1, A set O)
    int u = t + 1;
    writeA(rxO, ryO);                              // compiler waits A(u)
    if (u < 7) issueB((u + 1) * 64, 0);            // B(u+1) -> buf0
    if (u < 6) issueA((u + 2) * 64, rxO, ryO);     // A(u+2)
    if (u < 6) { WAITVM(16); } else { WAITVM(0); }
    WAITLGKM0;
    SBAR;
    SCHEDB;
    compute(1);
    SBAR;
  }

  // epilogue: bias + scale, direct stores (no n-panel loop: N=512 in-block)
#pragma unroll
  for (int ni = 0; ni < 8; ni++) {
    int col = wn4 * 128 + ni * 16 + qr;
    float bz = bias[col];
#pragma unroll
    for (int mi = 0; mi < 4; mi++) {
      int grb = m0 + wm2 * 64 + mi * 16 + quad * 4;
#pragma unroll
      for (int r = 0; r < 4; r++)
        C[(size_t)(grb + r) * 512 + col] = (bf16)((acc[mi][ni][r] + bz) * sc);
    }
  }
}

// ---------------------------------------------------------------------------
// Kernel 2b: V projection — r9's verified k_proj z==2 path verbatim
// (128x128 blocks, LDS-transpose epilogue to Vtp). grid (128,4), 256 thr.
// ---------------------------------------------------------------------------
__global__ __launch_bounds__(256, 3) void k_projV(
    const float* __restrict__ v, const bf16* __restrict__ Wt,
    const float* __restrict__ bv, bf16* __restrict__ Vtp) {
  const float* A = v;
  const float* bias = bv;
  const bf16* Bw = Wt + (size_t)2 * 262144;

  int m0 = blockIdx.x * 128, n0 = blockIdx.y * 128;
  __shared__ __align__(16) char smem[49152];
  bf16* As = (bf16*)smem;            // 128 x 64 single, swizzled (16 KB)
  bf16* Bs = (bf16*)(smem + 16384);  // 2 x (128 x 64), gload dbuf (32 KB)
  bf16* Ts = (bf16*)smem;            // epilogue reuse: 128 x 136

  int tid = threadIdx.x;
  int wave = tid >> 6, lane = tid & 63, qr = lane & 15, quad = lane >> 4;
  int wm = (wave >> 1) * 64, wn = (wave & 1) * 64;

  f32x4 acc[4][4];
  for (int mi = 0; mi < 4; mi++)
    for (int ni = 0; ni < 4; ni++) acc[mi][ni] = (f32x4){0.f, 0.f, 0.f, 0.f};

  float4 rxE[4], ryE[4];
  float4 rxO[4], ryO[4];

  auto issueA = [&](int kk, float4 (&rx)[4], float4 (&ry)[4]) {
#pragma unroll
    for (int i = 0; i < 4; i++) {
      int ch = i * 256 + tid, row = ch >> 3, c = ch & 7;
      const float4* src = (const float4*)(A + (size_t)(m0 + row) * 512 + kk + c * 8);
      rx[i] = src[0];
      ry[i] = src[1];
    }
    SCHEDB;
  };

  auto issueB = [&](int kk, int buf) {
#pragma unroll
    for (int i = 0; i < 4; i++) {
      int ch = i * 256 + tid, row = ch >> 3, c = ch & 7, cs = c ^ (row & 7);
      gload_lds16(Bw + (size_t)(n0 + row) * 512 + kk + cs * 8, &Bs[buf * 8192 + ch * 8]);
    }
    SCHEDB;
  };

  auto writeA = [&](float4 (&rx)[4], float4 (&ry)[4]) {
#pragma unroll
    for (int i = 0; i < 4; i++) {
      int ch = i * 256 + tid, row = ch >> 3, c = ch & 7, cs = c ^ (row & 7);
      bf16x8 t;
      t[0] = (bf16)rx[i].x; t[1] = (bf16)rx[i].y; t[2] = (bf16)rx[i].z; t[3] = (bf16)rx[i].w;
      t[4] = (bf16)ry[i].x; t[5] = (bf16)ry[i].y; t[6] = (bf16)ry[i].z; t[7] = (bf16)ry[i].w;
      *(bf16x8*)&As[row * 64 + cs * 8] = t;
    }
  };

  auto compute = [&](int buf) {
    bf16* Bb = &Bs[buf * 8192];
#pragma unroll
    for (int h = 0; h < 2; h++) {
      bf16x8 af[4], bfv[4];
#pragma unroll
      for (int mi = 0; mi < 4; mi++) {
        int rr = wm + mi * 16 + qr;
        int cc = (h * 4 + quad) ^ (rr & 7);
        af[mi] = *(bf16x8*)&As[rr * 64 + cc * 8];
      }
#pragma unroll
      for (int ni = 0; ni < 4; ni++) {
        int rr = wn + ni * 16 + qr;
        int cc = (h * 4 + quad) ^ (rr & 7);
        bfv[ni] = *(bf16x8*)&Bb[rr * 64 + cc * 8];
      }
#pragma unroll
      for (int mi = 0; mi < 4; mi++)
#pragma unroll
        for (int ni = 0; ni < 4; ni++) acc[mi][ni] = MFMA(af[mi], bfv[ni], acc[mi][ni]);
    }
  };

  issueA(0, rxE, ryE);
  issueB(0, 0);
  issueA(64, rxO, ryO);

#pragma unroll
  for (int t = 0; t < 8; t += 2) {
    writeA(rxE, ryE);
    issueB((t + 1) * 64, 1);
    if (t < 6) issueA((t + 2) * 64, rxE, ryE);
    if (t < 6) { WAITVM(20); } else { WAITVM(12); }
    WAITLGKM0;
    SBAR;
    SCHEDB;
    compute(0);
    SBAR;

    int u = t + 1;
    writeA(rxO, ryO);
    if (u < 7) issueB((u + 1) * 64, 0);
    if (u < 6) issueA((u + 2) * 64, rxO, ryO);
    if (u < 6) { WAITVM(20); } else if (u < 7) { WAITVM(12); } else { WAITVM(0); }
    WAITLGKM0;
    SBAR;
    SCHEDB;
    compute(1);
    SBAR;
  }

  // V epilogue: transpose via LDS, coalesced stores to Vtp[b*512+h][t]
  for (int ni = 0; ni < 4; ni++) {
    int hcol = wn + ni * 16 + qr;
    float bz = bias[n0 + hcol];
    for (int mi = 0; mi < 4; mi++) {
      int tl = wm + mi * 16 + quad * 4;
      bf16 tmp[4];
      for (int r = 0; r < 4; r++) tmp[r] = (bf16)(acc[mi][ni][r] + bz);
      *(uint64_t*)&Ts[hcol * 136 + tl] = *(uint64_t*)tmp;
    }
  }
  __syncthreads();
  int bb = m0 >> 11, t0l = m0 & 2047;
  for (int i = 0; i < 8; i++) {
    int ch = i * 256 + tid;
    int row = ch >> 4, c = ch & 15;
    *(bf16x8*)(Vtp + (size_t)(bb * 512 + n0 + row) * 2048 + t0l + c * 8) =
        *(bf16x8*)&Ts[row * 136 + c * 8];
  }
}

// ---------------------------------------------------------------------------
// Kernel 3: QK^T GEMM — 256x256, BK=64, 8 waves, COUNTED vmcnt (r9 verbatim).
// ---------------------------------------------------------------------------
__global__ __launch_bounds__(512, 1) void k_qk(const bf16* __restrict__ Qp,
                                               const bf16* __restrict__ Kp,
                                               bf16* __restrict__ P,
                                               float* __restrict__ Lpart) {
  __shared__ __align__(16) bf16 S[65536];  // A: [0,32768) 2 slots; B: [32768,65536)
  int id = blockIdx.x;
  int b = id & 7, j = id >> 3;
  int mx = j & 7, ny = j >> 3;
  const bf16* A = Qp + (size_t)b * 2048 * 512;
  const bf16* B = Kp + (size_t)b * 2048 * 512;
  bf16* Pb = P + (size_t)b * 2048 * 2048;
  int m0 = mx * 256, n0 = ny * 256;
  int tid = threadIdx.x;
  int wave = tid >> 6, lane = tid & 63, qr = lane & 15, quad = lane >> 4;
  int wm = wave >> 2, wn = wave & 3;  // 2M x 4N; wave tile 128 x 64

  f32x4 acc[8][4];
  for (int mi = 0; mi < 8; mi++)
    for (int ni = 0; ni < 4; ni++) acc[mi][ni] = (f32x4){0.f, 0.f, 0.f, 0.f};

  auto stageAj = [&](int t, int s, int jj) {
    int kk = t * 64;
    bf16* As_ = S + s * 16384;
    int ch = jj * 512 + tid, row = ch >> 3, c = ch & 7, cs = c ^ (row & 7);
    gload_lds16(A + (size_t)(m0 + row) * 512 + kk + cs * 8, As_ + ch * 8);
  };
  auto stage = [&](int t, int s) {
    int kk = t * 64;
    bf16* Bs_ = S + 32768 + s * 16384;
#pragma unroll
    for (int jj = 0; jj < 4; jj++) {
      int ch = jj * 512 + tid, row = ch >> 3, c = ch & 7, cs = c ^ (row & 7);
      gload_lds16(B + (size_t)(n0 + row) * 512 + kk + cs * 8, Bs_ + ch * 8);
    }
    stageAj(t, s, 0);
    stageAj(t, s, 2);
    stageAj(t, s, 1);
    stageAj(t, s, 3);
  };

  stage(0, 0);
  stage(1, 1);  // 16 loads/thread in flight

  for (int t = 0; t < 8; t++) {
    int cur = t & 1;
    bf16* As_ = S + cur * 16384;
    bf16* Bs_ = S + 32768 + cur * 16384;

    if (t < 7) { WAITVM(10); } else { WAITVM(2); }
    SBAR;
    bf16x8 aF[4][2], bF[4][2];
#pragma unroll
    for (int mi = 0; mi < 4; mi++)
#pragma unroll
      for (int kk = 0; kk < 2; kk++) {
        int row = wm * 128 + mi * 16 + qr;
        aF[mi][kk] = *(bf16x8*)&As_[row * 64 + ((kk * 4 + quad) ^ (row & 7)) * 8];
      }
#pragma unroll
    for (int ni = 0; ni < 4; ni++)
#pragma unroll
      for (int kk = 0; kk < 2; kk++) {
        int row = wn * 64 + ni * 16 + qr;
        bF[ni][kk] = *(bf16x8*)&Bs_[row * 64 + ((kk * 4 + quad) ^ (row & 7)) * 8];
      }
    WAITLGKM0;
    SCHEDB;
    PRIO(1);
#pragma unroll
    for (int kk = 0; kk < 2; kk++)
#pragma unroll
      for (int mi = 0; mi < 4; mi++)
#pragma unroll
        for (int ni = 0; ni < 4; ni++)
          acc[mi][ni] = MFMA(aF[mi][kk], bF[ni][kk], acc[mi][ni]);
    PRIO(0);

    if (t < 7) { WAITVM(8); } else { WAITVM(0); }
    SBAR;
#pragma unroll
    for (int mi = 0; mi < 4; mi++)
#pragma unroll
      for (int kk = 0; kk < 2; kk++) {
        int row = wm * 128 + 64 + mi * 16 + qr;
        aF[mi][kk] = *(bf16x8*)&As_[row * 64 + ((kk * 4 + quad) ^ (row & 7)) * 8];
      }
    WAITLGKM0;
    SBAR;
    if (t < 6) stage(t + 2, cur);
    SCHEDB;
    PRIO(1);
#pragma unroll
    for (int kk = 0; kk < 2; kk++)
#pragma unroll
      for (int mi = 0; mi < 4; mi++)
#pragma unroll
        for (int ni = 0; ni < 4; ni++)
          acc[4 + mi][ni] = MFMA(aF[mi][kk], bF[ni][kk], acc[4 + mi][ni]);
    PRIO(0);
  }

  int slice = ny * 4 + wn;  // 32 slices of 64 keys
  float* Lp = Lpart + (size_t)slice * 16384 + b * 2048;
#pragma unroll
  for (int mi = 0; mi < 8; mi++) {
    int rowb = m0 + wm * 128 + mi * 16 + quad * 4;
#pragma unroll
    for (int r = 0; r < 4; r++) {
      float s = 0.f;
      bf16* prow = Pb + (size_t)(rowb + r) * 2048 + n0 + wn * 64 + qr;
#pragma unroll
      for (int ni = 0; ni < 4; ni++) {
        float e = exp2f(acc[mi][ni][r] - M0);
        prow[ni * 16] = (bf16)e;
        s += e;
      }
      s += __shfl_xor(s, 1);
      s += __shfl_xor(s, 2);
      s += __shfl_xor(s, 4);
      s += __shfl_xor(s, 8);
      if (qr == 0) Lp[rowb + r] = s;
    }
  }
}

// ---------------------------------------------------------------------------
// Kernel 4: PV GEMM — 256x128, BK=64, 8 waves, COUNTED vmcnt (r9 verbatim).
// ---------------------------------------------------------------------------
__global__ __launch_bounds__(512, 1) void k_pv(const bf16* __restrict__ P,
                                               const bf16* __restrict__ Vtp,
                                               const float* __restrict__ Lpart,
                                               float* __restrict__ out) {
  __shared__ __align__(16) bf16 S[49152];
  int id = blockIdx.x;
  int b = id & 7, j = id >> 3;
  int mx = j & 7, ny = j >> 3;
  const bf16* A = P + (size_t)b * 2048 * 2048;
  const bf16* B = Vtp + (size_t)b * 512 * 2048;
  int m0 = mx * 256, n0 = ny * 128;
  int tid = threadIdx.x;
  int wave = tid >> 6, lane = tid & 63, qr = lane & 15, quad = lane >> 4;
  int wmi = wave >> 1, wni = wave & 1;

  float linv_own = 0.f;
  if (tid < 256) {
    float s = 0.f;
    for (int jj = 0; jj < 32; jj++) s += Lpart[(size_t)jj * 16384 + b * 2048 + m0 + tid];
    linv_own = 1.0f / s;
  }

  f32x4 acc[4][4];
  for (int mi = 0; mi < 4; mi++)
    for (int ni = 0; ni < 4; ni++) acc[mi][ni] = (f32x4){0.f, 0.f, 0.f, 0.f};

  auto stage = [&](int t, int s) {
    int kk = t * 64;
    bf16* As_ = S + s * 16384;
    bf16* Bs_ = S + 32768 + s * 8192;
#pragma unroll
    for (int jj = 0; jj < 4; jj++) {
      int ch = jj * 512 + tid, row = ch >> 3, c = ch & 7, cs = c ^ (row & 7);
      gload_lds16(A + (size_t)(m0 + row) * 2048 + kk + cs * 8, As_ + ch * 8);
    }
#pragma unroll
    for (int jj = 0; jj < 2; jj++) {
      int ch = jj * 512 + tid, row = ch >> 3, c = ch & 7, cs = c ^ (row & 7);
      gload_lds16(B + (size_t)(n0 + row) * 2048 + kk + cs * 8, Bs_ + ch * 8);
    }
  };

  stage(0, 0);
  stage(1, 1);  // 12 loads/thread in flight

  for (int t = 0; t < 32; t++) {
    int cur = t & 1;
    bf16* As_ = S + cur * 16384;
    bf16* Bs_ = S + 32768 + cur * 8192;

    if (t < 31) { WAITVM(6); } else { WAITVM(0); }
    SBAR;
    bf16x8 aF[4][2], bF[4][2];
#pragma unroll
    for (int mi = 0; mi < 4; mi++)
#pragma unroll
      for (int kk = 0; kk < 2; kk++) {
        int row = wmi * 64 + mi * 16 + qr;
        aF[mi][kk] = *(bf16x8*)&As_[row * 64 + ((kk * 4 + quad) ^ (row & 7)) * 8];
      }
#pragma unroll
    for (int ni = 0; ni < 4; ni++)
#pragma unroll
      for (int kk = 0; kk < 2; kk++) {
        int row = wni * 64 + ni * 16 + qr;
        bF[ni][kk] = *(bf16x8*)&Bs_[row * 64 + ((kk * 4 + quad) ^ (row & 7)) * 8];
      }
    WAITLGKM0;
    SBAR;
    if (t < 30) stage(t + 2, cur);
    SCHEDB;
    PRIO(1);
#pragma unroll
    for (int kk = 0; kk < 2; kk++)
#pragma unroll
      for (int mi = 0; mi < 4; mi++)
#pragma unroll
        for (int ni = 0; ni < 4; ni++)
          acc[mi][ni] = MFMA(aF[mi][kk], bF[ni][kk], acc[mi][ni]);
    PRIO(0);
  }

  WAITLGKM0;
  SBAR;
  float* Linv_s = (float*)S;
  if (tid < 256) Linv_s[tid] = linv_own;
  SBAR;

#pragma unroll
  for (int mi = 0; mi < 4; mi++) {
    int rowl = wmi * 64 + mi * 16 + quad * 4;
    float linv[4];
    for (int r = 0; r < 4; r++) linv[r] = Linv_s[rowl + r];
#pragma unroll
    for (int ni = 0; ni < 4; ni++) {
      int col = n0 + wni * 64 + ni * 16 + qr;
      float* og = out + (size_t)(b * 2048 + m0 + rowl) * 512 + col;
      for (int r = 0; r < 4; r++) og[(size_t)r * 512] = acc[mi][ni][r] * linv[r];
    }
  }
}

// ---------------------------------------------------------------------------
extern "C" void kernel_launch(void* const* d_in, const int* in_sizes, int n_in,
                              void* d_out, int out_size, void* d_ws, size_t ws_size,
                              hipStream_t stream) {
  (void)in_sizes; (void)n_in; (void)out_size; (void)ws_size;
  const float* q  = (const float*)d_in[0];
  const float* k  = (const float*)d_in[1];
  const float* v  = (const float*)d_in[2];
  const float* Wq = (const float*)d_in[3];
  const float* bq = (const float*)d_in[4];
  const float* Wk = (const float*)d_in[5];
  const float* bk = (const float*)d_in[6];
  const float* Wv = (const float*)d_in[7];
  const float* bv = (const float*)d_in[8];
  float* out = (float*)d_out;

  char* ws = (char*)d_ws;
  bf16* Wt     = (bf16*)(ws);                 // 1,572,864 B
  bf16* Qp     = (bf16*)(ws + 1572864);       // 16 MiB
  bf16* Kp     = (bf16*)(ws + 18350080);      // 16 MiB
  bf16* Vtp    = (bf16*)(ws + 35127296);      // 16 MiB
  bf16* P      = (bf16*)(ws + 51904512);      // 64 MiB
  float* Lpart = (float*)(ws + 119013376);    // 2 MiB  (total ~115.4 MiB)

  k_wtrans<<<dim3(16, 16, 3), dim3(32, 8, 1), 0, stream>>>(Wq, Wk, Wv, Wt);
  k_proj2<<<dim3(128, 2), 512, 147456, stream>>>(q, k, Wt, bq, bk, Qp, Kp);
  k_projV<<<dim3(128, 4), 256, 0, stream>>>(v, Wt, bv, Vtp);
  k_qk<<<512, 512, 0, stream>>>(Qp, Kp, P, Lpart);
  k_pv<<<256, 512, 0, stream>>>(P, Vtp, Lpart, out);
}